// Round 10
// baseline (218.843 us; speedup 1.0000x reference)
//
#include <hip/hip_runtime.h>
#include <stdint.h>

typedef unsigned short u16;
typedef unsigned int u32;
typedef __attribute__((ext_vector_type(8))) short s8v;   // 8 bf16 = 4 VGPR (MFMA A/B frag)
typedef __attribute__((ext_vector_type(4))) float f4v;   // MFMA C/D frag
typedef __attribute__((ext_vector_type(8))) u16 u16x8;
typedef __attribute__((ext_vector_type(4))) u16 u16x4;

// ---------- bf16 helpers ----------
__device__ __forceinline__ float bf2f(u16 u){
  union { u32 i; float f; } v; v.i = ((u32)u) << 16; return v.f;
}
__device__ __forceinline__ u16 f2bf(float f){
  union { float f; u32 i; } v; v.f = f;
  u32 i = v.i;
  return (u16)((i + 0x7fffu + ((i >> 16) & 1u)) >> 16); // RNE
}
__device__ __forceinline__ float sgnf(float w){
  return (w > 0.f) ? 1.f : ((w < 0.f) ? -1.f : 0.f);
}
__device__ __forceinline__ u16 sgn_bf(float w){
  return (w > 0.f) ? (u16)0x3F80 : ((w < 0.f) ? (u16)0xBF80 : (u16)0);
}

// async global->LDS, 16B per lane, wave-uniform LDS base + lane*16
#define GLL16(gaddr, laddr) __builtin_amdgcn_global_load_lds( \
    (const __attribute__((address_space(1))) void*)(gaddr),   \
    (__attribute__((address_space(3))) void*)(laddr), 16, 0, 0)

// R23 channel permutation for conv1-out/conv2-in (64 channels):
// position p holds original channel orig(p) = (p&3)*16 + (p>>2)
// (p = l15*4 + nt). Lets conv1m store u16x4 per lane instead of 4 scalar u16.

// ---------- merged weight prep: sign-gen for w1/w2/wfc2 (blocks 0..305) +
// wfc1 sign + k-permute via LDS transpose (blocks 306..561).
// Spread partials (4x256) + k_red4 (R18's single-line atomics cost +21us).
// R23: qw2b k-dim generated in PERMUTED conv2-input-channel order. ----------
__global__ __launch_bounds__(256) void k_gen(const float* __restrict__ w1, const float* __restrict__ w2,
                                             const float* __restrict__ wfc2, const float* __restrict__ wfc1,
                                             u16* __restrict__ qw1b, u16* __restrict__ qw2b,
                                             float* __restrict__ qwfc2, u16* __restrict__ qfc1b,
                                             float* __restrict__ partials){
  __shared__ u16 tile[128*72];   // [c][px], row pad 64->72 (18 KB) -- fc1gen branch only
  int t = threadIdx.x;
  if (blockIdx.x < 306){
    int i = blockIdx.x * 256 + t;
    float av = 0.f; int slot;
    if (i < 73728){
      int j = i & 7, lane = (i >> 3) & 63, fid = i >> 9;    // 0..143
      int s = fid >> 4, ks = (fid >> 3) & 1, nt = fid & 7;
      int co = (lane & 15)*8 + nt;
      int c_pos = ks*32 + (lane >> 4)*8 + j;                // position in permuted k-order
      int c6 = c_pos & 63;
      int c_orig = ((c6 & 3) << 4) + (c6 >> 2);             // orig(p)
      float wv = w2[((size_t)co*64 + c_orig)*9 + s];
      qw2b[i] = sgn_bf(wv);
      av = fabsf(wv); slot = 1;
    } else if (i < 73728 + 2048){
      int i3 = i - 73728;
      int j = i3 & 7, lane = (i3 >> 3) & 63, nt = i3 >> 9;  // 0..3
      int co = nt*16 + (lane & 15);
      int k = (lane >> 4)*8 + j;
      if (k < 27){
        float wv = w1[co*27 + k];
        qw1b[i3] = sgn_bf(wv);
        av = fabsf(wv);
      } else qw1b[i3] = (u16)0;
      slot = 0;
    } else {
      int i4 = i - (73728 + 2048);
      float wv = wfc2[i4];
      qwfc2[i4] = sgnf(wv);
      av = fabsf(wv); slot = 3;
    }
    #pragma unroll
    for (int off = 32; off > 0; off >>= 1) av += __shfl_xor(av, off);
    if ((t & 63) == 0) atomicAdd(partials + slot*256 + (blockIdx.x & 255), av);
  } else {
    int co = blockIdx.x - 306;
    const float4* src = (const float4*)(wfc1 + (size_t)co*8192);
    float av = 0.f;
    #pragma unroll
    for (int p = 0; p < 8; ++p){
      int k4 = t + p*256;              // float4 index; k_src = k4*4
      float4 v = src[k4];
      int c = k4 >> 4, px = (k4 & 15)*4;   // k_src>>6, k_src&63
      u16* d = tile + c*72 + px;
      d[0] = sgn_bf(v.x); d[1] = sgn_bf(v.y); d[2] = sgn_bf(v.z); d[3] = sgn_bf(v.w);
      av += fabsf(v.x) + fabsf(v.y) + fabsf(v.z) + fabsf(v.w);
    }
    #pragma unroll
    for (int off = 32; off > 0; off >>= 1) av += __shfl_xor(av, off);
    if ((t & 63) == 0) atomicAdd(partials + 2*256 + (co & 255), av);
    __syncthreads();
    int co4 = co >> 4, co15 = co & 15;
    #pragma unroll
    for (int p = 0; p < 4; ++p){
      int m = t + p*256;               // chunk id = px*16 + jj
      int px = m >> 4, jj = m & 15;
      int kstep = px*4 + (jj >> 2), l16 = jj & 3;
      u16x8 o;
      #pragma unroll
      for (int u = 0; u < 8; ++u) o[u] = tile[(jj*8 + u)*72 + px];
      *(u16x8*)(qfc1b + ((size_t)(kstep*16 + co4)*512 + (l16*16 + co15)*8)) = o;
    }
  }
}

// ---------- reduce 4x256 partials -> absum[4] ----------
__global__ void k_red4(const float* __restrict__ partials, float* __restrict__ absum){
  int t = threadIdx.x, w = t >> 6, lane = t & 63;
  const float* p = partials + w*256;
  float s = p[lane] + p[lane + 64] + p[lane + 128] + p[lane + 192];
  #pragma unroll
  for (int off = 32; off > 0; off >>= 1) s += __shfl_xor(s, off);
  if (lane == 0) absum[w] = s;
}

// ---------- conv1 via MFMA. R20 direct per-lane im2col + R23 permuted-channel
// output: lane's 4 pooled co values are contiguous at position l15*4+nt -> one
// u16x4 (8B) store per tile instead of 4 scalar u16 (64 -> 16 stores/thread).
// BN1 stats accumulated at permuted positions (consumers read positionally). ----------
__global__ __launch_bounds__(256) void k_conv1m(const float* __restrict__ x, const u16* __restrict__ qw1b,
                                                const float* __restrict__ absum, u16* __restrict__ p1raw,
                                                float* __restrict__ gs, float* __restrict__ gq){
  __shared__ __align__(8) u16 xs[3*34*36];       // bf16 halo image (7.2 KB), data y=1..32, x=2..33
  __shared__ float ls1[64], ls2[64];
  int n = blockIdx.x, t = threadIdx.x;
  if (t < 64){ ls1[t] = 0.f; ls2[t] = 0.f; }
  for (int i = t; i < 1836; i += 256) ((u32*)xs)[i] = 0u;   // 3672 u16 = 1836 u32
  __syncthreads();
  const float4* xg = (const float4*)(x + (size_t)n * 3072);
  for (int i = t; i < 768; i += 256){
    float4 v = xg[i];
    int ci = i >> 8, rem = i & 255, y = rem >> 3, xq = (rem & 7) * 4;
    int base = ci*1224 + (y+1)*36 + 2 + xq;      // even -> u32-aligned
    *(u32*)(xs + base)     = (u32)f2bf(v.x) | ((u32)f2bf(v.y) << 16);
    *(u32*)(xs + base + 2) = (u32)f2bf(v.z) | ((u32)f2bf(v.w) << 16);
  }
  int w = t >> 6, lane = t & 63, l15 = lane & 15, q = lane >> 4;
  // per-thread k-decode: k = q*8+j -> xs offset (u16 units) + zero mask for k>=27
  int koff[8]; u32 kmsk[8];
  #pragma unroll
  for (int j = 0; j < 8; ++j){
    int k = q*8 + j;
    int d9 = (k*57) >> 9;          // k/9 for k<32
    int r9 = k - d9*9;
    int d3 = (r9*11) >> 5;         // r9/3 for r9<9
    int r3 = r9 - d3*3;
    koff[j] = d9*1224 + d3*36 + r3;
    kmsk[j] = (k < 27) ? 0xffffu : 0u;
  }
  const s8v* bp = (const s8v*)qw1b;
  s8v bf[4];
  #pragma unroll
  for (int nt = 0; nt < 4; ++nt) bf[nt] = bp[nt*64 + lane];
  float alpha = absum[0] * (1.f/1728.f);
  u16* p1img = p1raw + (size_t)n * 16384;
  float s1v[4], s2v[4];
  #pragma unroll
  for (int nt = 0; nt < 4; ++nt){ s1v[nt] = 0.f; s2v[nt] = 0.f; }
  __syncthreads();                 // xs ready; only barrier in the kernel body
  for (int chunk = 0; chunk < 4; ++chunk){
    #pragma unroll
    for (int i = 0; i < 4; ++i){
      int tl = w*4 + i;
      int r = tl*16 + l15;
      int g = (chunk*256 + r) >> 2, s = r & 3;
      int iy = 2*(g >> 4) + (s >> 1), ix = 2*(g & 15) + (s & 1);
      const u16* xb = xs + iy*36 + ix + 1;
      u32 pk2[4];
      #pragma unroll
      for (int kk = 0; kk < 4; ++kk){
        u32 lo = (u32)xb[koff[2*kk]]     & kmsk[2*kk];
        u32 hi = (u32)xb[koff[2*kk + 1]] & kmsk[2*kk + 1];
        pk2[kk] = lo | (hi << 16);
      }
      s8v av;
      ((u32*)&av)[0] = pk2[0]; ((u32*)&av)[1] = pk2[1];
      ((u32*)&av)[2] = pk2[2]; ((u32*)&av)[3] = pk2[3];
      int go = chunk*64 + tl*4 + q;
      u16x4 pk;
      #pragma unroll
      for (int nt = 0; nt < 4; ++nt){
        f4v c = (f4v)(0.0f);
        c = __builtin_amdgcn_mfma_f32_16x16x32_bf16(av, bf[nt], c, 0, 0, 0);
        s1v[nt] += c[0] + c[1] + c[2] + c[3];
        s2v[nt] += c[0]*c[0] + c[1]*c[1] + c[2]*c[2] + c[3]*c[3];
        float pm = fmaxf(fmaxf(c[0], c[1]), fmaxf(c[2], c[3]));
        pk[nt] = f2bf(pm * alpha);
      }
      *(u16x4*)(p1img + go*64 + l15*4) = pk;   // permuted: position l15*4+nt
    }
  }
  #pragma unroll
  for (int nt = 0; nt < 4; ++nt){
    s1v[nt] += __shfl_xor(s1v[nt], 16); s1v[nt] += __shfl_xor(s1v[nt], 32);
    s2v[nt] += __shfl_xor(s2v[nt], 16); s2v[nt] += __shfl_xor(s2v[nt], 32);
  }
  if (q == 0){
    #pragma unroll
    for (int nt = 0; nt < 4; ++nt){
      atomicAdd(&ls1[l15*4 + nt], s1v[nt]);    // permuted position
      atomicAdd(&ls2[l15*4 + nt], s2v[nt]);
    }
  }
  __syncthreads();
  if (t < 64){
    atomicAdd(gs + t, ls1[t] * alpha);
    atomicAdd(gq + t, ls2[t] * alpha * alpha);
  }
}

// ---------- conv2 via MFMA. PARKED structure (R20 3-ring, counted vmcnt(1), raw
// s_barrier; 7 attacks R14-R21 all 61-63us). R23: 2x 512-block dispatches (n0)
// for top-5 visibility below 62us (proven neutral, R17); g1/b1 gathered through
// orig(p) since p1t channel positions are permuted (s1/q1 are position-indexed). ----------
__global__ __launch_bounds__(512, 4) void k_conv2m(const u16* __restrict__ p1raw, const u16* __restrict__ qw2b,
                                                   const float* __restrict__ absum,
                                                   const float* __restrict__ s1, const float* __restrict__ q1,
                                                   const float* __restrict__ g1, const float* __restrict__ b1,
                                                   u16* __restrict__ p2raw,
                                                   float* __restrict__ gs, float* __restrict__ gq, int n0){
  __shared__ __align__(16) u16 img[288*64];      // 36 KB halo image; reused for stats after compute
  __shared__ __align__(16) u16 bstage[3][4096];  // 3 x 8 KB B-block ring
  int n = blockIdx.x + n0, t = threadIdx.x;
  int c0 = (t & 7) * 8;
  float scv[8], biv[8];
  #pragma unroll
  for (int j = 0; j < 8; ++j){
    int cp = c0 + j;
    int corig = ((cp & 3) << 4) + (cp >> 2);     // original channel for this position
    float m = s1[cp] * (1.f/1048576.f);
    float var = q1[cp] * (1.f/1048576.f) - m*m;
    float sc = g1[corig] * rsqrtf(var + 1e-5f);
    scv[j] = sc; biv[j] = b1[corig] - m*sc;
  }
  // zero the x-halo columns (col 0 and col 17)
  if (t < 256){
    int cl = t >> 7, y = (t >> 3) & 15, unit = t & 7;
    int px = y*18 + cl*17;
    int su = unit ^ (px & 7);
    *(u16x8*)(img + px*64 + su*8) = (u16x8)(u16)0;
  }
  const u16* src = p1raw + (size_t)n * 16384;
  #pragma unroll
  for (int i = 0; i < 4; ++i){
    int id = i*512 + t;            // = p0*8 + unit, unit == t&7
    int p0 = id >> 3, unit = id & 7;
    int y = p0 >> 4, xq = p0 & 15;
    int px = y*18 + xq + 1;
    int su = unit ^ (px & 7);
    u16x8 v = *(const u16x8*)(src + id*8);
    u16x8 o;
    #pragma unroll
    for (int j = 0; j < 8; ++j)
      o[j] = f2bf(fmaxf(bf2f(v[j]) * scv[j] + biv[j], 0.f));
    *(u16x8*)(img + px*64 + su*8) = o;
  }
  int w = t >> 6, lane = t & 63, l15 = lane & 15, q = lane >> 4;
  int wr = w >> 1, wc = w & 1;
  const char* bsrc = (const char*)qw2b;
  {
    const char* g = bsrc + w*1024 + lane*16;
    GLL16(g, ((char*)bstage[0]) + w*1024);
  }
  __syncthreads();
  f4v acc[4][4];
  #pragma unroll
  for (int a = 0; a < 4; ++a)
    #pragma unroll
    for (int b = 0; b < 4; ++b) acc[a][b] = (f4v)(0.0f);
  for (int p = 0; p < 18; ++p){
    int s = p >> 1, ks = p & 1;
    int dy = s / 3, dx = s - dy*3;
    if (p < 17){
      const char* g = bsrc + (size_t)(p + 1)*8192 + w*1024 + lane*16;
      GLL16(g, ((char*)bstage[(p + 1) % 3]) + w*1024);
      asm volatile("s_waitcnt vmcnt(1)" ::: "memory");
    } else {
      asm volatile("s_waitcnt vmcnt(0)" ::: "memory");
    }
    __builtin_amdgcn_s_barrier();   // raw: does NOT drain in-flight prefetch
    asm volatile("" ::: "memory");
    const u16* bb = bstage[p % 3];
    s8v bf[4];
    #pragma unroll
    for (int nt = 0; nt < 4; ++nt) bf[nt] = *(const s8v*)(bb + ((wc*4 + nt)*64 + lane)*8);
    __builtin_amdgcn_s_setprio(1);
    #pragma unroll
    for (int mt = 0; mt < 4; ++mt){
      int yv = wr*4 + mt + dy - 1;
      if (yv >= 0 && yv <= 15){
        int px = yv*18 + l15 + dx;       // halo cols give zeros at x = -1/16
        int su = (ks*4 + q) ^ (px & 7);
        s8v av = *(const s8v*)(img + px*64 + su*8);
        #pragma unroll
        for (int nt = 0; nt < 4; ++nt)
          acc[mt][nt] = __builtin_amdgcn_mfma_f32_16x16x32_bf16(av, bf[nt], acc[mt][nt], 0, 0, 0);
      }
    }
    __builtin_amdgcn_s_setprio(0);
  }
  float alpha = absum[1] * (1.f/73728.f);
  float s1v[4], s2v[4];
  #pragma unroll
  for (int nt = 0; nt < 4; ++nt){ s1v[nt] = 0.f; s2v[nt] = 0.f; }
  #pragma unroll
  for (int mp = 0; mp < 2; ++mp){
    #pragma unroll
    for (int rp = 0; rp < 2; ++rp){
      u16x4 pk;
      #pragma unroll
      for (int nt = 0; nt < 4; ++nt){
        float v0 = acc[2*mp][nt][2*rp]     * alpha;
        float v1 = acc[2*mp][nt][2*rp+1]   * alpha;
        float v2 = acc[2*mp+1][nt][2*rp]   * alpha;
        float v3 = acc[2*mp+1][nt][2*rp+1] * alpha;
        s1v[nt] += v0 + v1 + v2 + v3;
        s2v[nt] += v0*v0 + v1*v1 + v2*v2 + v3*v3;
        pk[nt] = f2bf(fmaxf(fmaxf(v0, v1), fmaxf(v2, v3)));
      }
      int opx = (wr*2 + mp)*8 + (q*2 + rp);  // pooled 8x8 index
      *(u16x4*)(p2raw + ((size_t)n*64 + opx)*128 + l15*8 + wc*4) = pk;
    }
  }
  #pragma unroll
  for (int nt = 0; nt < 4; ++nt){
    s1v[nt] += __shfl_xor(s1v[nt], 16); s1v[nt] += __shfl_xor(s1v[nt], 32);
    s2v[nt] += __shfl_xor(s2v[nt], 16); s2v[nt] += __shfl_xor(s2v[nt], 32);
  }
  __syncthreads();                 // all waves done reading img -> reuse as stats LDS
  float* ls = (float*)img;         // ls[0..127]=sum, ls[128..255]=sumsq
  if (t < 256) ls[t] = 0.f;
  __syncthreads();
  if (q == 0){
    #pragma unroll
    for (int nt = 0; nt < 4; ++nt){
      atomicAdd(&ls[l15*8 + wc*4 + nt], s1v[nt]);
      atomicAdd(&ls[128 + l15*8 + wc*4 + nt], s2v[nt]);
    }
  }
  __syncthreads();
  if (t < 128){ atomicAdd(gs + t, ls[t]); atomicAdd(gq + t, ls[128 + t]); }
}

// ---------- fc1 via MFMA. R22 structure: BN2+ReLU fused into the A-load (no k_bn2
// kernel; channel-octet-ordered ks loop so scv/biv computed 4x/thread); kb=8.
// grid (32,2,8)=512 blocks; wave tile 16 rows x 64 co, acc[1][4]; 2 blocks/CU. ----------
__global__ __launch_bounds__(256) void k_fc1m(const u16* __restrict__ p2, const u16* __restrict__ qfc1b,
                                              const float* __restrict__ absum,
                                              const float* __restrict__ s2, const float* __restrict__ q2,
                                              const float* __restrict__ g2, const float* __restrict__ b2,
                                              float* __restrict__ h3p){
  int t = threadIdx.x;
  int bm = blockIdx.x, bn = blockIdx.y, kb = blockIdx.z;
  int w = t >> 6, lane = t & 63, l15 = lane & 15, q = lane >> 4;
  int wr = w >> 1, wc = w & 1;
  int rowbase = bm*32 + wr*16;
  int ntb = bn*8 + wc*4;
  const s8v* bp = (const s8v*)qfc1b;
  f4v acc[4];
  #pragma unroll
  for (int b = 0; b < 4; ++b) acc[b] = (f4v)(0.0f);
  #pragma unroll
  for (int ks4 = 0; ks4 < 4; ++ks4){
    int c0 = ks4*32 + q*8;
    float scv[8], biv[8];
    #pragma unroll
    for (int j = 0; j < 8; ++j){
      float m = s2[c0+j] * (1.f/262144.f);
      float var = q2[c0+j] * (1.f/262144.f) - m*m;
      float sc = g2[c0+j] * rsqrtf(var + 1e-5f);
      scv[j] = sc; biv[j] = b2[c0+j] - m*sc;
    }
    #pragma unroll 2
    for (int u = 0; u < 8; ++u){
      int ks = ks4 + u*4;
      int kst = kb*32 + ks;
      s8v bf[4];
      #pragma unroll
      for (int nt = 0; nt < 4; ++nt) bf[nt] = bp[(kst*16 + ntb + nt)*64 + lane];
      u16x8 araw = *(const u16x8*)(p2 + (size_t)(rowbase + l15)*8192 + kst*32 + q*8);
      s8v av;
      #pragma unroll
      for (int j = 0; j < 8; ++j){
        float f = fmaxf(bf2f(araw[j]) * scv[j] + biv[j], 0.f);
        ((u16*)&av)[j] = f2bf(f);
      }
      #pragma unroll
      for (int nt = 0; nt < 4; ++nt)
        acc[nt] = __builtin_amdgcn_mfma_f32_16x16x32_bf16(av, bf[nt], acc[nt], 0, 0, 0);
    }
  }
  float alpha = absum[2] * (1.f/2097152.f);
  float* dst = h3p + (size_t)kb * 262144;
  #pragma unroll
  for (int nt = 0; nt < 4; ++nt){
    int col = (ntb + nt)*16 + l15;
    #pragma unroll
    for (int r = 0; r < 4; ++r)
      dst[(size_t)(rowbase + q*4 + r)*256 + col] = acc[nt][r] * alpha;
  }
}

// ---------- reduce k-split slabs (kb=8) + BN3 stats + materialize h3.
// grid (8,64)=512 blocks; each block: 32 j x 16 n, 2 elems/thread. ----------
__global__ __launch_bounds__(256) void k_fin3f(const float* __restrict__ h3p, float* __restrict__ h3,
                                               float* __restrict__ s3, float* __restrict__ q3){
  int jb = blockIdx.x, ns = blockIdx.y, t = threadIdx.x;
  int jj = t & 31, nn = t >> 5;
  int j = jb*32 + jj;
  float s1 = 0.f, s2 = 0.f;
  #pragma unroll
  for (int i = 0; i < 2; ++i){
    int n = ns*16 + i*8 + nn;
    float v = 0.f;
    #pragma unroll
    for (int kb = 0; kb < 8; ++kb) v += h3p[(size_t)kb*262144 + n*256 + j];
    h3[n*256 + j] = v;
    s1 += v; s2 += v*v;
  }
  __shared__ float l1[256], l2[256];
  l1[t] = s1; l2[t] = s2;
  __syncthreads();
  if (t < 32){
    float a = 0.f, b = 0.f;
    #pragma unroll
    for (int k = 0; k < 8; ++k){ a += l1[t+32*k]; b += l2[t+32*k]; }
    atomicAdd(s3 + jb*32 + t, a); atomicAdd(q3 + jb*32 + t, b);
  }
}

// ---------- fc2: relu(bn3(h3)) @ sign(wfc2)^T -> out[1024,10] fp32 (BN3 params inline) ----------
__global__ __launch_bounds__(64) void k_fc2(const float* __restrict__ h3, const float* __restrict__ qwfc2,
                                            const float* __restrict__ absum,
                                            const float* __restrict__ s3, const float* __restrict__ q3,
                                            const float* __restrict__ g3, const float* __restrict__ b3,
                                            float* __restrict__ out){
  int n = blockIdx.x, lane = threadIdx.x;
  float a[4];
  #pragma unroll
  for (int i = 0; i < 4; ++i){
    int j = lane + 64*i;
    float m = s3[j] * (1.f/1024.f);
    float var = q3[j] * (1.f/1024.f) - m*m;
    float sc = g3[j] * rsqrtf(var + 1e-5f);
    float v = h3[(size_t)n*256 + j] * sc + (b3[j] - m*sc);
    a[i] = fmaxf(v, 0.f);
  }
  float alpha = absum[3] * (1.f/2560.f);
  #pragma unroll
  for (int k = 0; k < 10; ++k){
    float p = 0.f;
    #pragma unroll
    for (int i = 0; i < 4; ++i) p += a[i] * qwfc2[k*256 + lane + 64*i];
    #pragma unroll
    for (int off = 32; off > 0; off >>= 1) p += __shfl_down(p, off);
    if (lane == 0) out[n*10 + k] = p * alpha;
  }
}

extern "C" void kernel_launch(void* const* d_in, const int* in_sizes, int n_in,
                              void* d_out, int out_size, void* d_ws, size_t ws_size,
                              hipStream_t stream){
  (void)in_sizes; (void)n_in; (void)out_size; (void)ws_size;
  const float* x    = (const float*)d_in[0];
  const float* w1   = (const float*)d_in[1];
  const float* g1   = (const float*)d_in[2];
  const float* b1   = (const float*)d_in[3];
  const float* w2   = (const float*)d_in[4];
  const float* g2   = (const float*)d_in[5];
  const float* b2   = (const float*)d_in[6];
  const float* wfc1 = (const float*)d_in[7];
  const float* g3   = (const float*)d_in[8];
  const float* b3   = (const float*)d_in[9];
  const float* wfc2 = (const float*)d_in[10];
  float* out = (float*)d_out;

  float* wsf = (float*)d_ws;
  char*  wsb = (char*)d_ws;
  float* absum = wsf;
  float* s1 = wsf + 16;   float* q1 = wsf + 80;
  float* s2 = wsf + 144;  float* q2 = wsf + 272;
  float* s3 = wsf + 1024; float* q3 = wsf + 1280;
  float* partials = wsf + 2048;                      // 4x256 fp32 (zeroed)
  u16*   qw1b  = (u16*)(wsf + 4096);                 // 2048 u16 conv1 B-frags
  u16*   qw2b  = (u16*)(wsb + (64u << 10));          // 144 KB bf16 B-frags
  float* qwfc2 = (float*)(wsb + (256u << 10));       // 10 KB fp32
  float* h3    = (float*)(wsb + (1ull << 20));       // 1 MB fp32 [1024][256]
  u16*   qfc1b = (u16*)(wsb + (2ull << 20));         // 4 MB bf16 B-frags
  u16*   p1t   = (u16*)(wsb + (8ull << 20) + 4096);  // 32 MB bf16 [1024][256][64] (permuted channels)
  u16*   p2    = (u16*)(wsb + (112ull << 20));       // 16 MB bf16 [1024][64][128] pooled raw (BN2 fused into fc1m)
  float* h3p   = (float*)(wsb + (128ull << 20));     // 8 MB fp32 [8][1024][256]

  hipMemsetAsync(wsf, 0, 3072 * sizeof(float), stream);
  k_gen<<<562, 256, 0, stream>>>(w1, w2, wfc2, wfc1, qw1b, qw2b, qwfc2, qfc1b, partials);
  k_red4<<<1, 256, 0, stream>>>(partials, absum);
  k_conv1m<<<1024, 256, 0, stream>>>(x, qw1b, absum, p1t, s1, q1);
  k_conv2m<<<512, 512, 0, stream>>>(p1t, qw2b, absum, s1, q1, g1, b1, p2, s2, q2, 0);
  k_conv2m<<<512, 512, 0, stream>>>(p1t, qw2b, absum, s1, q1, g1, b1, p2, s2, q2, 512);
  k_fc1m<<<dim3(32, 2, 8), 256, 0, stream>>>(p2, qfc1b, absum, s2, q2, g2, b2, h3p);
  k_fin3f<<<dim3(8, 64), 256, 0, stream>>>(h3p, h3, s3, q3);
  k_fc2<<<1024, 64, 0, stream>>>(h3, qwfc2, absum, s3, q3, g3, b3, out);
}

// Round 11
// 213.625 us; speedup vs baseline: 1.0244x; 1.0244x over previous
//
#include <hip/hip_runtime.h>
#include <stdint.h>

typedef unsigned short u16;
typedef unsigned int u32;
typedef __attribute__((ext_vector_type(8))) short s8v;   // 8 bf16 = 4 VGPR (MFMA A/B frag)
typedef __attribute__((ext_vector_type(4))) float f4v;   // MFMA C/D frag
typedef __attribute__((ext_vector_type(8))) u16 u16x8;
typedef __attribute__((ext_vector_type(4))) u16 u16x4;

// ---------- bf16 helpers ----------
__device__ __forceinline__ float bf2f(u16 u){
  union { u32 i; float f; } v; v.i = ((u32)u) << 16; return v.f;
}
__device__ __forceinline__ u16 f2bf(float f){
  union { float f; u32 i; } v; v.f = f;
  u32 i = v.i;
  return (u16)((i + 0x7fffu + ((i >> 16) & 1u)) >> 16); // RNE
}
__device__ __forceinline__ float sgnf(float w){
  return (w > 0.f) ? 1.f : ((w < 0.f) ? -1.f : 0.f);
}
__device__ __forceinline__ u16 sgn_bf(float w){
  return (w > 0.f) ? (u16)0x3F80 : ((w < 0.f) ? (u16)0xBF80 : (u16)0);
}

// async global->LDS, 16B per lane, wave-uniform LDS base + lane*16
#define GLL16(gaddr, laddr) __builtin_amdgcn_global_load_lds( \
    (const __attribute__((address_space(1))) void*)(gaddr),   \
    (__attribute__((address_space(3))) void*)(laddr), 16, 0, 0)

// R23 channel permutation for conv1-out/conv2-in (64 channels):
// position p holds original channel orig(p) = (p&3)*16 + (p>>2)  (p = l15*4 + nt).
//
// R24 KEY SIMPLIFICATION -- BatchNorm scale-invariance: BN(a*x) == BN(x) for a>0,
// and maxpool commutes with a>0. So the BitNet alphas for conv1/conv2/fc1 cancel
// exactly (each is immediately followed by a BN). Only alpha4 (fc2, no BN after)
// survives -> absum[0..2] chain + k_red4 dispatch DELETED; absum[3] via 40 direct
// atomics in k_gen's wfc2 blocks (far below R18's 2.2k-atomic contention regime).

// ---------- merged weight prep: sign-gen for w1/w2/wfc2 (blocks 0..305) +
// wfc1 sign + k-permute via LDS transpose (blocks 306..561).
// qw2b k-dim generated in PERMUTED conv2-input-channel order (R23). ----------
__global__ __launch_bounds__(256) void k_gen(const float* __restrict__ w1, const float* __restrict__ w2,
                                             const float* __restrict__ wfc2, const float* __restrict__ wfc1,
                                             u16* __restrict__ qw1b, u16* __restrict__ qw2b,
                                             float* __restrict__ qwfc2, u16* __restrict__ qfc1b,
                                             float* __restrict__ absum){
  __shared__ u16 tile[128*72];   // [c][px], row pad 64->72 (18 KB) -- fc1gen branch only
  int t = threadIdx.x;
  if (blockIdx.x < 306){
    int i = blockIdx.x * 256 + t;
    if (i < 73728){
      int j = i & 7, lane = (i >> 3) & 63, fid = i >> 9;    // 0..143
      int s = fid >> 4, ks = (fid >> 3) & 1, nt = fid & 7;
      int co = (lane & 15)*8 + nt;
      int c_pos = ks*32 + (lane >> 4)*8 + j;                // position in permuted k-order
      int c6 = c_pos & 63;
      int c_orig = ((c6 & 3) << 4) + (c6 >> 2);             // orig(p)
      qw2b[i] = sgn_bf(w2[((size_t)co*64 + c_orig)*9 + s]);
    } else if (i < 73728 + 2048){
      int i3 = i - 73728;
      int j = i3 & 7, lane = (i3 >> 3) & 63, nt = i3 >> 9;  // 0..3
      int co = nt*16 + (lane & 15);
      int k = (lane >> 4)*8 + j;
      qw1b[i3] = (k < 27) ? sgn_bf(w1[co*27 + k]) : (u16)0;
    } else {
      int i4 = i - (73728 + 2048);
      float wv = wfc2[i4];
      qwfc2[i4] = sgnf(wv);
      float av = fabsf(wv);
      #pragma unroll
      for (int off = 32; off > 0; off >>= 1) av += __shfl_xor(av, off);
      if ((t & 63) == 0) atomicAdd(absum + 3, av);          // 40 atomics total
    }
  } else {
    int co = blockIdx.x - 306;
    const float4* src = (const float4*)(wfc1 + (size_t)co*8192);
    #pragma unroll
    for (int p = 0; p < 8; ++p){
      int k4 = t + p*256;              // float4 index; k_src = k4*4
      float4 v = src[k4];
      int c = k4 >> 4, px = (k4 & 15)*4;   // k_src>>6, k_src&63
      u16* d = tile + c*72 + px;
      d[0] = sgn_bf(v.x); d[1] = sgn_bf(v.y); d[2] = sgn_bf(v.z); d[3] = sgn_bf(v.w);
    }
    __syncthreads();
    int co4 = co >> 4, co15 = co & 15;
    #pragma unroll
    for (int p = 0; p < 4; ++p){
      int m = t + p*256;               // chunk id = px*16 + jj
      int px = m >> 4, jj = m & 15;
      int kstep = px*4 + (jj >> 2), l16 = jj & 3;
      u16x8 o;
      #pragma unroll
      for (int u = 0; u < 8; ++u) o[u] = tile[(jj*8 + u)*72 + px];
      *(u16x8*)(qfc1b + ((size_t)(kstep*16 + co4)*512 + (l16*16 + co15)*8)) = o;
    }
  }
}

// ---------- conv1 via MFMA. R20 direct per-lane im2col + R23 permuted-channel
// u16x4 stores. R24: NO alpha (BN1 absorbs it) -> no absum dependency at all. ----------
__global__ __launch_bounds__(256) void k_conv1m(const float* __restrict__ x, const u16* __restrict__ qw1b,
                                                u16* __restrict__ p1raw,
                                                float* __restrict__ gs, float* __restrict__ gq){
  __shared__ __align__(8) u16 xs[3*34*36];       // bf16 halo image (7.2 KB), data y=1..32, x=2..33
  __shared__ float ls1[64], ls2[64];
  int n = blockIdx.x, t = threadIdx.x;
  if (t < 64){ ls1[t] = 0.f; ls2[t] = 0.f; }
  for (int i = t; i < 1836; i += 256) ((u32*)xs)[i] = 0u;   // 3672 u16 = 1836 u32
  __syncthreads();
  const float4* xg = (const float4*)(x + (size_t)n * 3072);
  for (int i = t; i < 768; i += 256){
    float4 v = xg[i];
    int ci = i >> 8, rem = i & 255, y = rem >> 3, xq = (rem & 7) * 4;
    int base = ci*1224 + (y+1)*36 + 2 + xq;      // even -> u32-aligned
    *(u32*)(xs + base)     = (u32)f2bf(v.x) | ((u32)f2bf(v.y) << 16);
    *(u32*)(xs + base + 2) = (u32)f2bf(v.z) | ((u32)f2bf(v.w) << 16);
  }
  int w = t >> 6, lane = t & 63, l15 = lane & 15, q = lane >> 4;
  // per-thread k-decode: k = q*8+j -> xs offset (u16 units) + zero mask for k>=27
  int koff[8]; u32 kmsk[8];
  #pragma unroll
  for (int j = 0; j < 8; ++j){
    int k = q*8 + j;
    int d9 = (k*57) >> 9;          // k/9 for k<32
    int r9 = k - d9*9;
    int d3 = (r9*11) >> 5;         // r9/3 for r9<9
    int r3 = r9 - d3*3;
    koff[j] = d9*1224 + d3*36 + r3;
    kmsk[j] = (k < 27) ? 0xffffu : 0u;
  }
  const s8v* bp = (const s8v*)qw1b;
  s8v bf[4];
  #pragma unroll
  for (int nt = 0; nt < 4; ++nt) bf[nt] = bp[nt*64 + lane];
  u16* p1img = p1raw + (size_t)n * 16384;
  float s1v[4], s2v[4];
  #pragma unroll
  for (int nt = 0; nt < 4; ++nt){ s1v[nt] = 0.f; s2v[nt] = 0.f; }
  __syncthreads();                 // xs ready; only barrier in the kernel body
  for (int chunk = 0; chunk < 4; ++chunk){
    #pragma unroll
    for (int i = 0; i < 4; ++i){
      int tl = w*4 + i;
      int r = tl*16 + l15;
      int g = (chunk*256 + r) >> 2, s = r & 3;
      int iy = 2*(g >> 4) + (s >> 1), ix = 2*(g & 15) + (s & 1);
      const u16* xb = xs + iy*36 + ix + 1;
      u32 pk2[4];
      #pragma unroll
      for (int kk = 0; kk < 4; ++kk){
        u32 lo = (u32)xb[koff[2*kk]]     & kmsk[2*kk];
        u32 hi = (u32)xb[koff[2*kk + 1]] & kmsk[2*kk + 1];
        pk2[kk] = lo | (hi << 16);
      }
      s8v av;
      ((u32*)&av)[0] = pk2[0]; ((u32*)&av)[1] = pk2[1];
      ((u32*)&av)[2] = pk2[2]; ((u32*)&av)[3] = pk2[3];
      int go = chunk*64 + tl*4 + q;
      u16x4 pk;
      #pragma unroll
      for (int nt = 0; nt < 4; ++nt){
        f4v c = (f4v)(0.0f);
        c = __builtin_amdgcn_mfma_f32_16x16x32_bf16(av, bf[nt], c, 0, 0, 0);
        s1v[nt] += c[0] + c[1] + c[2] + c[3];
        s2v[nt] += c[0]*c[0] + c[1]*c[1] + c[2]*c[2] + c[3]*c[3];
        float pm = fmaxf(fmaxf(c[0], c[1]), fmaxf(c[2], c[3]));
        pk[nt] = f2bf(pm);           // raw, unscaled (BN1 absorbs alpha)
      }
      *(u16x4*)(p1img + go*64 + l15*4) = pk;   // permuted: position l15*4+nt
    }
  }
  #pragma unroll
  for (int nt = 0; nt < 4; ++nt){
    s1v[nt] += __shfl_xor(s1v[nt], 16); s1v[nt] += __shfl_xor(s1v[nt], 32);
    s2v[nt] += __shfl_xor(s2v[nt], 16); s2v[nt] += __shfl_xor(s2v[nt], 32);
  }
  if (q == 0){
    #pragma unroll
    for (int nt = 0; nt < 4; ++nt){
      atomicAdd(&ls1[l15*4 + nt], s1v[nt]);    // permuted position
      atomicAdd(&ls2[l15*4 + nt], s2v[nt]);
    }
  }
  __syncthreads();
  if (t < 64){
    atomicAdd(gs + t, ls1[t]);
    atomicAdd(gq + t, ls2[t]);
  }
}

// ---------- conv2 via MFMA. PARKED structure (R20 3-ring, counted vmcnt(1), raw
// s_barrier; 7 attacks R14-R21 all 61-63us). Single 1024-block dispatch (R22 best).
// R24: no alpha (BN2 absorbs); g1/b1 gathered through orig(p) (permuted positions). ----------
__global__ __launch_bounds__(512, 4) void k_conv2m(const u16* __restrict__ p1raw, const u16* __restrict__ qw2b,
                                                   const float* __restrict__ s1, const float* __restrict__ q1,
                                                   const float* __restrict__ g1, const float* __restrict__ b1,
                                                   u16* __restrict__ p2raw,
                                                   float* __restrict__ gs, float* __restrict__ gq){
  __shared__ __align__(16) u16 img[288*64];      // 36 KB halo image; reused for stats after compute
  __shared__ __align__(16) u16 bstage[3][4096];  // 3 x 8 KB B-block ring
  int n = blockIdx.x, t = threadIdx.x;
  int c0 = (t & 7) * 8;
  float scv[8], biv[8];
  #pragma unroll
  for (int j = 0; j < 8; ++j){
    int cp = c0 + j;
    int corig = ((cp & 3) << 4) + (cp >> 2);     // original channel for this position
    float m = s1[cp] * (1.f/1048576.f);
    float var = q1[cp] * (1.f/1048576.f) - m*m;
    float sc = g1[corig] * rsqrtf(var + 1e-5f);
    scv[j] = sc; biv[j] = b1[corig] - m*sc;
  }
  // zero the x-halo columns (col 0 and col 17)
  if (t < 256){
    int cl = t >> 7, y = (t >> 3) & 15, unit = t & 7;
    int px = y*18 + cl*17;
    int su = unit ^ (px & 7);
    *(u16x8*)(img + px*64 + su*8) = (u16x8)(u16)0;
  }
  const u16* src = p1raw + (size_t)n * 16384;
  #pragma unroll
  for (int i = 0; i < 4; ++i){
    int id = i*512 + t;            // = p0*8 + unit, unit == t&7
    int p0 = id >> 3, unit = id & 7;
    int y = p0 >> 4, xq = p0 & 15;
    int px = y*18 + xq + 1;
    int su = unit ^ (px & 7);
    u16x8 v = *(const u16x8*)(src + id*8);
    u16x8 o;
    #pragma unroll
    for (int j = 0; j < 8; ++j)
      o[j] = f2bf(fmaxf(bf2f(v[j]) * scv[j] + biv[j], 0.f));
    *(u16x8*)(img + px*64 + su*8) = o;
  }
  int w = t >> 6, lane = t & 63, l15 = lane & 15, q = lane >> 4;
  int wr = w >> 1, wc = w & 1;
  const char* bsrc = (const char*)qw2b;
  {
    const char* g = bsrc + w*1024 + lane*16;
    GLL16(g, ((char*)bstage[0]) + w*1024);
  }
  __syncthreads();
  f4v acc[4][4];
  #pragma unroll
  for (int a = 0; a < 4; ++a)
    #pragma unroll
    for (int b = 0; b < 4; ++b) acc[a][b] = (f4v)(0.0f);
  for (int p = 0; p < 18; ++p){
    int s = p >> 1, ks = p & 1;
    int dy = s / 3, dx = s - dy*3;
    if (p < 17){
      const char* g = bsrc + (size_t)(p + 1)*8192 + w*1024 + lane*16;
      GLL16(g, ((char*)bstage[(p + 1) % 3]) + w*1024);
      asm volatile("s_waitcnt vmcnt(1)" ::: "memory");
    } else {
      asm volatile("s_waitcnt vmcnt(0)" ::: "memory");
    }
    __builtin_amdgcn_s_barrier();   // raw: does NOT drain in-flight prefetch
    asm volatile("" ::: "memory");
    const u16* bb = bstage[p % 3];
    s8v bf[4];
    #pragma unroll
    for (int nt = 0; nt < 4; ++nt) bf[nt] = *(const s8v*)(bb + ((wc*4 + nt)*64 + lane)*8);
    __builtin_amdgcn_s_setprio(1);
    #pragma unroll
    for (int mt = 0; mt < 4; ++mt){
      int yv = wr*4 + mt + dy - 1;
      if (yv >= 0 && yv <= 15){
        int px = yv*18 + l15 + dx;       // halo cols give zeros at x = -1/16
        int su = (ks*4 + q) ^ (px & 7);
        s8v av = *(const s8v*)(img + px*64 + su*8);
        #pragma unroll
        for (int nt = 0; nt < 4; ++nt)
          acc[mt][nt] = __builtin_amdgcn_mfma_f32_16x16x32_bf16(av, bf[nt], acc[mt][nt], 0, 0, 0);
      }
    }
    __builtin_amdgcn_s_setprio(0);
  }
  float s1v[4], s2v[4];
  #pragma unroll
  for (int nt = 0; nt < 4; ++nt){ s1v[nt] = 0.f; s2v[nt] = 0.f; }
  #pragma unroll
  for (int mp = 0; mp < 2; ++mp){
    #pragma unroll
    for (int rp = 0; rp < 2; ++rp){
      u16x4 pk;
      #pragma unroll
      for (int nt = 0; nt < 4; ++nt){
        float v0 = acc[2*mp][nt][2*rp];
        float v1 = acc[2*mp][nt][2*rp+1];
        float v2 = acc[2*mp+1][nt][2*rp];
        float v3 = acc[2*mp+1][nt][2*rp+1];
        s1v[nt] += v0 + v1 + v2 + v3;
        s2v[nt] += v0*v0 + v1*v1 + v2*v2 + v3*v3;
        pk[nt] = f2bf(fmaxf(fmaxf(v0, v1), fmaxf(v2, v3)));   // raw (BN2 absorbs alpha)
      }
      int opx = (wr*2 + mp)*8 + (q*2 + rp);  // pooled 8x8 index
      *(u16x4*)(p2raw + ((size_t)n*64 + opx)*128 + l15*8 + wc*4) = pk;
    }
  }
  #pragma unroll
  for (int nt = 0; nt < 4; ++nt){
    s1v[nt] += __shfl_xor(s1v[nt], 16); s1v[nt] += __shfl_xor(s1v[nt], 32);
    s2v[nt] += __shfl_xor(s2v[nt], 16); s2v[nt] += __shfl_xor(s2v[nt], 32);
  }
  __syncthreads();                 // all waves done reading img -> reuse as stats LDS
  float* ls = (float*)img;         // ls[0..127]=sum, ls[128..255]=sumsq
  if (t < 256) ls[t] = 0.f;
  __syncthreads();
  if (q == 0){
    #pragma unroll
    for (int nt = 0; nt < 4; ++nt){
      atomicAdd(&ls[l15*8 + wc*4 + nt], s1v[nt]);
      atomicAdd(&ls[128 + l15*8 + wc*4 + nt], s2v[nt]);
    }
  }
  __syncthreads();
  if (t < 128){ atomicAdd(gs + t, ls[t]); atomicAdd(gq + t, ls[128 + t]); }
}

// ---------- fc1 via MFMA. BN2+ReLU fused into the A-load (channel-octet-ordered
// ks loop); kb=8; R24: no alpha (BN3 absorbs). grid (32,2,8)=512 blocks. ----------
__global__ __launch_bounds__(256) void k_fc1m(const u16* __restrict__ p2, const u16* __restrict__ qfc1b,
                                              const float* __restrict__ s2, const float* __restrict__ q2,
                                              const float* __restrict__ g2, const float* __restrict__ b2,
                                              float* __restrict__ h3p){
  int t = threadIdx.x;
  int bm = blockIdx.x, bn = blockIdx.y, kb = blockIdx.z;
  int w = t >> 6, lane = t & 63, l15 = lane & 15, q = lane >> 4;
  int wr = w >> 1, wc = w & 1;
  int rowbase = bm*32 + wr*16;
  int ntb = bn*8 + wc*4;
  const s8v* bp = (const s8v*)qfc1b;
  f4v acc[4];
  #pragma unroll
  for (int b = 0; b < 4; ++b) acc[b] = (f4v)(0.0f);
  #pragma unroll
  for (int ks4 = 0; ks4 < 4; ++ks4){
    int c0 = ks4*32 + q*8;
    float scv[8], biv[8];
    #pragma unroll
    for (int j = 0; j < 8; ++j){
      float m = s2[c0+j] * (1.f/262144.f);
      float var = q2[c0+j] * (1.f/262144.f) - m*m;
      float sc = g2[c0+j] * rsqrtf(var + 1e-5f);
      scv[j] = sc; biv[j] = b2[c0+j] - m*sc;
    }
    #pragma unroll 2
    for (int u = 0; u < 8; ++u){
      int ks = ks4 + u*4;
      int kst = kb*32 + ks;
      s8v bf[4];
      #pragma unroll
      for (int nt = 0; nt < 4; ++nt) bf[nt] = bp[(kst*16 + ntb + nt)*64 + lane];
      u16x8 araw = *(const u16x8*)(p2 + (size_t)(rowbase + l15)*8192 + kst*32 + q*8);
      s8v av;
      #pragma unroll
      for (int j = 0; j < 8; ++j){
        float f = fmaxf(bf2f(araw[j]) * scv[j] + biv[j], 0.f);
        ((u16*)&av)[j] = f2bf(f);
      }
      #pragma unroll
      for (int nt = 0; nt < 4; ++nt)
        acc[nt] = __builtin_amdgcn_mfma_f32_16x16x32_bf16(av, bf[nt], acc[nt], 0, 0, 0);
    }
  }
  float* dst = h3p + (size_t)kb * 262144;
  #pragma unroll
  for (int nt = 0; nt < 4; ++nt){
    int col = (ntb + nt)*16 + l15;
    #pragma unroll
    for (int r = 0; r < 4; ++r)
      dst[(size_t)(rowbase + q*4 + r)*256 + col] = acc[nt][r];   // raw (BN3 absorbs alpha)
  }
}

// ---------- reduce k-split slabs (kb=8) + BN3 stats + materialize h3.
// grid (8,64)=512 blocks; each block: 32 j x 16 n, 2 elems/thread. ----------
__global__ __launch_bounds__(256) void k_fin3f(const float* __restrict__ h3p, float* __restrict__ h3,
                                               float* __restrict__ s3, float* __restrict__ q3){
  int jb = blockIdx.x, ns = blockIdx.y, t = threadIdx.x;
  int jj = t & 31, nn = t >> 5;
  int j = jb*32 + jj;
  float s1 = 0.f, s2 = 0.f;
  #pragma unroll
  for (int i = 0; i < 2; ++i){
    int n = ns*16 + i*8 + nn;
    float v = 0.f;
    #pragma unroll
    for (int kb = 0; kb < 8; ++kb) v += h3p[(size_t)kb*262144 + n*256 + j];
    h3[n*256 + j] = v;
    s1 += v; s2 += v*v;
  }
  __shared__ float l1[256], l2[256];
  l1[t] = s1; l2[t] = s2;
  __syncthreads();
  if (t < 32){
    float a = 0.f, b = 0.f;
    #pragma unroll
    for (int k = 0; k < 8; ++k){ a += l1[t+32*k]; b += l2[t+32*k]; }
    atomicAdd(s3 + jb*32 + t, a); atomicAdd(q3 + jb*32 + t, b);
  }
}

// ---------- fc2: relu(bn3(h3)) @ sign(wfc2)^T -> out[1024,10] fp32.
// R24: 256 blocks x 256 threads (4 rows/block, 1 row/wave; fewer tiny blocks). ----------
__global__ __launch_bounds__(256) void k_fc2(const float* __restrict__ h3, const float* __restrict__ qwfc2,
                                             const float* __restrict__ absum,
                                             const float* __restrict__ s3, const float* __restrict__ q3,
                                             const float* __restrict__ g3, const float* __restrict__ b3,
                                             float* __restrict__ out){
  int t = threadIdx.x;
  int n = blockIdx.x*4 + (t >> 6), lane = t & 63;
  float a[4];
  #pragma unroll
  for (int i = 0; i < 4; ++i){
    int j = lane + 64*i;
    float m = s3[j] * (1.f/1024.f);
    float var = q3[j] * (1.f/1024.f) - m*m;
    float sc = g3[j] * rsqrtf(var + 1e-5f);
    float v = h3[(size_t)n*256 + j] * sc + (b3[j] - m*sc);
    a[i] = fmaxf(v, 0.f);
  }
  float alpha = absum[3] * (1.f/2560.f);
  #pragma unroll
  for (int k = 0; k < 10; ++k){
    float p = 0.f;
    #pragma unroll
    for (int i = 0; i < 4; ++i) p += a[i] * qwfc2[k*256 + lane + 64*i];
    #pragma unroll
    for (int off = 32; off > 0; off >>= 1) p += __shfl_down(p, off);
    if (lane == 0) out[n*10 + k] = p * alpha;
  }
}

extern "C" void kernel_launch(void* const* d_in, const int* in_sizes, int n_in,
                              void* d_out, int out_size, void* d_ws, size_t ws_size,
                              hipStream_t stream){
  (void)in_sizes; (void)n_in; (void)out_size; (void)ws_size;
  const float* x    = (const float*)d_in[0];
  const float* w1   = (const float*)d_in[1];
  const float* g1   = (const float*)d_in[2];
  const float* b1   = (const float*)d_in[3];
  const float* w2   = (const float*)d_in[4];
  const float* g2   = (const float*)d_in[5];
  const float* b2   = (const float*)d_in[6];
  const float* wfc1 = (const float*)d_in[7];
  const float* g3   = (const float*)d_in[8];
  const float* b3   = (const float*)d_in[9];
  const float* wfc2 = (const float*)d_in[10];
  float* out = (float*)d_out;

  float* wsf = (float*)d_ws;
  char*  wsb = (char*)d_ws;
  float* absum = wsf;                                // [4] (only slot 3 used)
  float* s1 = wsf + 16;   float* q1 = wsf + 80;
  float* s2 = wsf + 144;  float* q2 = wsf + 272;
  float* s3 = wsf + 1024; float* q3 = wsf + 1280;
  u16*   qw1b  = (u16*)(wsf + 4096);                 // 2048 u16 conv1 B-frags
  u16*   qw2b  = (u16*)(wsb + (64u << 10));          // 144 KB bf16 B-frags
  float* qwfc2 = (float*)(wsb + (256u << 10));       // 10 KB fp32
  float* h3    = (float*)(wsb + (1ull << 20));       // 1 MB fp32 [1024][256]
  u16*   qfc1b = (u16*)(wsb + (2ull << 20));         // 4 MB bf16 B-frags
  u16*   p1t   = (u16*)(wsb + (8ull << 20) + 4096);  // 32 MB bf16 [1024][256][64] (permuted channels)
  u16*   p2    = (u16*)(wsb + (112ull << 20));       // 16 MB bf16 [1024][64][128] pooled raw (BN2 fused into fc1m)
  float* h3p   = (float*)(wsb + (128ull << 20));     // 8 MB fp32 [8][1024][256]

  hipMemsetAsync(wsf, 0, 2048 * sizeof(float), stream);
  k_gen<<<562, 256, 0, stream>>>(w1, w2, wfc2, wfc1, qw1b, qw2b, qwfc2, qfc1b, absum);
  k_conv1m<<<1024, 256, 0, stream>>>(x, qw1b, p1t, s1, q1);
  k_conv2m<<<1024, 512, 0, stream>>>(p1t, qw2b, s1, q1, g1, b1, p2, s2, q2);
  k_fc1m<<<dim3(32, 2, 8), 256, 0, stream>>>(p2, qfc1b, s2, q2, g2, b2, h3p);
  k_fin3f<<<dim3(8, 64), 256, 0, stream>>>(h3p, h3, s3, q3);
  k_fc2<<<256, 256, 0, stream>>>(h3, qwfc2, absum, s3, q3, g3, b3, out);
}

// Round 12
// 209.317 us; speedup vs baseline: 1.0455x; 1.0206x over previous
//
#include <hip/hip_runtime.h>
#include <stdint.h>

typedef unsigned short u16;
typedef unsigned int u32;
typedef __attribute__((ext_vector_type(8))) short s8v;   // 8 bf16 = 4 VGPR (MFMA A/B frag)
typedef __attribute__((ext_vector_type(4))) float f4v;   // MFMA C/D frag
typedef __attribute__((ext_vector_type(8))) u16 u16x8;
typedef __attribute__((ext_vector_type(4))) u16 u16x4;

// ---------- bf16 helpers ----------
__device__ __forceinline__ float bf2f(u16 u){
  union { u32 i; float f; } v; v.i = ((u32)u) << 16; return v.f;
}
__device__ __forceinline__ u16 f2bf(float f){
  union { float f; u32 i; } v; v.f = f;
  u32 i = v.i;
  return (u16)((i + 0x7fffu + ((i >> 16) & 1u)) >> 16); // RNE
}
__device__ __forceinline__ float sgnf(float w){
  return (w > 0.f) ? 1.f : ((w < 0.f) ? -1.f : 0.f);
}
__device__ __forceinline__ u16 sgn_bf(float w){
  return (w > 0.f) ? (u16)0x3F80 : ((w < 0.f) ? (u16)0xBF80 : (u16)0);
}

// async global->LDS, 16B per lane, wave-uniform LDS base + lane*16
#define GLL16(gaddr, laddr) __builtin_amdgcn_global_load_lds( \
    (const __attribute__((address_space(1))) void*)(gaddr),   \
    (__attribute__((address_space(3))) void*)(laddr), 16, 0, 0)

// R23 channel permutation for conv1-out/conv2-in (64 channels):
// position p holds original channel orig(p) = (p&3)*16 + (p>>2)  (p = l15*4 + nt).
// R24: BN scale-invariance -> alphas for conv1/conv2/fc1 cancel (BN absorbs);
// only alpha4 survives (absum[3], 40 direct atomics in k_gen).
// R25: (a) conv2m 9-phase (2 taps' worth of K per barrier: 32 MFMA + bf[2][4],
// 2x16KB B-pair ring, GLL issued AFTER the barrier -> 2-buffer ring is race-free);
// (b) h3p DELETED -- fc1m atomicAdds kb-partials into L2-resident h3 (zeroed in
// k_gen); fin3f is a stats-only 1MB pass.

// ---------- merged weight prep + h3 zeroing ----------
__global__ __launch_bounds__(256) void k_gen(const float* __restrict__ w1, const float* __restrict__ w2,
                                             const float* __restrict__ wfc2, const float* __restrict__ wfc1,
                                             u16* __restrict__ qw1b, u16* __restrict__ qw2b,
                                             float* __restrict__ qwfc2, u16* __restrict__ qfc1b,
                                             float* __restrict__ absum, float* __restrict__ h3){
  __shared__ u16 tile[128*72];   // [c][px], row pad 64->72 (18 KB) -- fc1gen branch only
  int t = threadIdx.x;
  if (blockIdx.x < 256){
    // zero h3 (1MB): 256 blocks x 256 threads x 1 float4
    *(float4*)(h3 + ((size_t)blockIdx.x*256 + t)*4) = make_float4(0.f, 0.f, 0.f, 0.f);
  }
  if (blockIdx.x < 306){
    int i = blockIdx.x * 256 + t;
    if (i < 73728){
      int j = i & 7, lane = (i >> 3) & 63, fid = i >> 9;    // 0..143
      int s = fid >> 4, ks = (fid >> 3) & 1, nt = fid & 7;
      int co = (lane & 15)*8 + nt;
      int c_pos = ks*32 + (lane >> 4)*8 + j;                // position in permuted k-order
      int c6 = c_pos & 63;
      int c_orig = ((c6 & 3) << 4) + (c6 >> 2);             // orig(p)
      qw2b[i] = sgn_bf(w2[((size_t)co*64 + c_orig)*9 + s]);
    } else if (i < 73728 + 2048){
      int i3 = i - 73728;
      int j = i3 & 7, lane = (i3 >> 3) & 63, nt = i3 >> 9;  // 0..3
      int co = nt*16 + (lane & 15);
      int k = (lane >> 4)*8 + j;
      qw1b[i3] = (k < 27) ? sgn_bf(w1[co*27 + k]) : (u16)0;
    } else {
      int i4 = i - (73728 + 2048);
      float wv = wfc2[i4];
      qwfc2[i4] = sgnf(wv);
      float av = fabsf(wv);
      #pragma unroll
      for (int off = 32; off > 0; off >>= 1) av += __shfl_xor(av, off);
      if ((t & 63) == 0) atomicAdd(absum + 3, av);          // 40 atomics total
    }
  } else {
    int co = blockIdx.x - 306;
    const float4* src = (const float4*)(wfc1 + (size_t)co*8192);
    #pragma unroll
    for (int p = 0; p < 8; ++p){
      int k4 = t + p*256;              // float4 index; k_src = k4*4
      float4 v = src[k4];
      int c = k4 >> 4, px = (k4 & 15)*4;   // k_src>>6, k_src&63
      u16* d = tile + c*72 + px;
      d[0] = sgn_bf(v.x); d[1] = sgn_bf(v.y); d[2] = sgn_bf(v.z); d[3] = sgn_bf(v.w);
    }
    __syncthreads();
    int co4 = co >> 4, co15 = co & 15;
    #pragma unroll
    for (int p = 0; p < 4; ++p){
      int m = t + p*256;               // chunk id = px*16 + jj
      int px = m >> 4, jj = m & 15;
      int kstep = px*4 + (jj >> 2), l16 = jj & 3;
      u16x8 o;
      #pragma unroll
      for (int u = 0; u < 8; ++u) o[u] = tile[(jj*8 + u)*72 + px];
      *(u16x8*)(qfc1b + ((size_t)(kstep*16 + co4)*512 + (l16*16 + co15)*8)) = o;
    }
  }
}

// ---------- conv1 via MFMA. R20 direct per-lane im2col + R23 permuted-channel
// u16x4 stores; no alpha (BN1 absorbs). ----------
__global__ __launch_bounds__(256) void k_conv1m(const float* __restrict__ x, const u16* __restrict__ qw1b,
                                                u16* __restrict__ p1raw,
                                                float* __restrict__ gs, float* __restrict__ gq){
  __shared__ __align__(8) u16 xs[3*34*36];       // bf16 halo image (7.2 KB), data y=1..32, x=2..33
  __shared__ float ls1[64], ls2[64];
  int n = blockIdx.x, t = threadIdx.x;
  if (t < 64){ ls1[t] = 0.f; ls2[t] = 0.f; }
  for (int i = t; i < 1836; i += 256) ((u32*)xs)[i] = 0u;   // 3672 u16 = 1836 u32
  __syncthreads();
  const float4* xg = (const float4*)(x + (size_t)n * 3072);
  for (int i = t; i < 768; i += 256){
    float4 v = xg[i];
    int ci = i >> 8, rem = i & 255, y = rem >> 3, xq = (rem & 7) * 4;
    int base = ci*1224 + (y+1)*36 + 2 + xq;      // even -> u32-aligned
    *(u32*)(xs + base)     = (u32)f2bf(v.x) | ((u32)f2bf(v.y) << 16);
    *(u32*)(xs + base + 2) = (u32)f2bf(v.z) | ((u32)f2bf(v.w) << 16);
  }
  int w = t >> 6, lane = t & 63, l15 = lane & 15, q = lane >> 4;
  int koff[8]; u32 kmsk[8];
  #pragma unroll
  for (int j = 0; j < 8; ++j){
    int k = q*8 + j;
    int d9 = (k*57) >> 9;          // k/9 for k<32
    int r9 = k - d9*9;
    int d3 = (r9*11) >> 5;         // r9/3 for r9<9
    int r3 = r9 - d3*3;
    koff[j] = d9*1224 + d3*36 + r3;
    kmsk[j] = (k < 27) ? 0xffffu : 0u;
  }
  const s8v* bp = (const s8v*)qw1b;
  s8v bf[4];
  #pragma unroll
  for (int nt = 0; nt < 4; ++nt) bf[nt] = bp[nt*64 + lane];
  u16* p1img = p1raw + (size_t)n * 16384;
  float s1v[4], s2v[4];
  #pragma unroll
  for (int nt = 0; nt < 4; ++nt){ s1v[nt] = 0.f; s2v[nt] = 0.f; }
  __syncthreads();                 // xs ready; only barrier in the kernel body
  for (int chunk = 0; chunk < 4; ++chunk){
    #pragma unroll
    for (int i = 0; i < 4; ++i){
      int tl = w*4 + i;
      int r = tl*16 + l15;
      int g = (chunk*256 + r) >> 2, s = r & 3;
      int iy = 2*(g >> 4) + (s >> 1), ix = 2*(g & 15) + (s & 1);
      const u16* xb = xs + iy*36 + ix + 1;
      u32 pk2[4];
      #pragma unroll
      for (int kk = 0; kk < 4; ++kk){
        u32 lo = (u32)xb[koff[2*kk]]     & kmsk[2*kk];
        u32 hi = (u32)xb[koff[2*kk + 1]] & kmsk[2*kk + 1];
        pk2[kk] = lo | (hi << 16);
      }
      s8v av;
      ((u32*)&av)[0] = pk2[0]; ((u32*)&av)[1] = pk2[1];
      ((u32*)&av)[2] = pk2[2]; ((u32*)&av)[3] = pk2[3];
      int go = chunk*64 + tl*4 + q;
      u16x4 pk;
      #pragma unroll
      for (int nt = 0; nt < 4; ++nt){
        f4v c = (f4v)(0.0f);
        c = __builtin_amdgcn_mfma_f32_16x16x32_bf16(av, bf[nt], c, 0, 0, 0);
        s1v[nt] += c[0] + c[1] + c[2] + c[3];
        s2v[nt] += c[0]*c[0] + c[1]*c[1] + c[2]*c[2] + c[3]*c[3];
        float pm = fmaxf(fmaxf(c[0], c[1]), fmaxf(c[2], c[3]));
        pk[nt] = f2bf(pm);           // raw, unscaled (BN1 absorbs alpha)
      }
      *(u16x4*)(p1img + go*64 + l15*4) = pk;   // permuted: position l15*4+nt
    }
  }
  #pragma unroll
  for (int nt = 0; nt < 4; ++nt){
    s1v[nt] += __shfl_xor(s1v[nt], 16); s1v[nt] += __shfl_xor(s1v[nt], 32);
    s2v[nt] += __shfl_xor(s2v[nt], 16); s2v[nt] += __shfl_xor(s2v[nt], 32);
  }
  if (q == 0){
    #pragma unroll
    for (int nt = 0; nt < 4; ++nt){
      atomicAdd(&ls1[l15*4 + nt], s1v[nt]);    // permuted position
      atomicAdd(&ls2[l15*4 + nt], s2v[nt]);
    }
  }
  __syncthreads();
  if (t < 64){
    atomicAdd(gs + t, ls1[t]);
    atomicAdd(gq + t, ls2[t]);
  }
}

// ---------- conv2 via MFMA. R25: 9-phase schedule -- one barrier per TAP (was
// per tap-half): 32 MFMA + 16 ds_read_b128 per barrier (2x K-work/barrier; m233:
// stage+vmcnt+barrier dominates 2-phase critical paths). B staged as contiguous
// 16KB pairs (chunks 2p,2p+1) into a 2-buffer ring. Race-free ordering: GLL for
// pair p+1 issued AFTER barrier p (laggards done reading buf[(p+1)&1]); vmcnt(0)
// sits after the 32-MFMA cluster (~450cy cover). LDS 36+32=68KB -> 2 blocks/CU. ----------
__global__ __launch_bounds__(512, 4) void k_conv2m(const u16* __restrict__ p1raw, const u16* __restrict__ qw2b,
                                                   const float* __restrict__ s1, const float* __restrict__ q1,
                                                   const float* __restrict__ g1, const float* __restrict__ b1,
                                                   u16* __restrict__ p2raw,
                                                   float* __restrict__ gs, float* __restrict__ gq){
  __shared__ __align__(16) u16 img[288*64];      // 36 KB halo image; reused for stats after compute
  __shared__ __align__(16) u16 bstage[2][8192];  // 2 x 16 KB B-pair ring
  int n = blockIdx.x, t = threadIdx.x;
  int c0 = (t & 7) * 8;
  float scv[8], biv[8];
  #pragma unroll
  for (int j = 0; j < 8; ++j){
    int cp = c0 + j;
    int corig = ((cp & 3) << 4) + (cp >> 2);     // original channel for this position
    float m = s1[cp] * (1.f/1048576.f);
    float var = q1[cp] * (1.f/1048576.f) - m*m;
    float sc = g1[corig] * rsqrtf(var + 1e-5f);
    scv[j] = sc; biv[j] = b1[corig] - m*sc;
  }
  // zero the x-halo columns (col 0 and col 17)
  if (t < 256){
    int cl = t >> 7, y = (t >> 3) & 15, unit = t & 7;
    int px = y*18 + cl*17;
    int su = unit ^ (px & 7);
    *(u16x8*)(img + px*64 + su*8) = (u16x8)(u16)0;
  }
  const u16* src = p1raw + (size_t)n * 16384;
  #pragma unroll
  for (int i = 0; i < 4; ++i){
    int id = i*512 + t;            // = p0*8 + unit, unit == t&7
    int p0 = id >> 3, unit = id & 7;
    int y = p0 >> 4, xq = p0 & 15;
    int px = y*18 + xq + 1;
    int su = unit ^ (px & 7);
    u16x8 v = *(const u16x8*)(src + id*8);
    u16x8 o;
    #pragma unroll
    for (int j = 0; j < 8; ++j)
      o[j] = f2bf(fmaxf(bf2f(v[j]) * scv[j] + biv[j], 0.f));
    *(u16x8*)(img + px*64 + su*8) = o;
  }
  int w = t >> 6, lane = t & 63, l15 = lane & 15, q = lane >> 4;
  int wr = w >> 1, wc = w & 1;
  const char* bsrc = (const char*)qw2b;
  // prologue: stage pair 0 (wave w stages 2KB); __syncthreads drains vmcnt.
  {
    const char* g = bsrc + w*2048 + lane*16;
    char* l = ((char*)bstage[0]) + w*2048;
    GLL16(g, l); GLL16(g + 1024, l + 1024);
  }
  __syncthreads();
  f4v acc[4][4];
  #pragma unroll
  for (int a = 0; a < 4; ++a)
    #pragma unroll
    for (int b = 0; b < 4; ++b) acc[a][b] = (f4v)(0.0f);
  for (int p = 0; p < 9; ++p){     // one phase per tap; both ks halves inside
    int dy = p / 3, dx = p - dy*3;
    if (p < 8){                    // issue pair p+1 AFTER the barrier we arrived through
      const char* g = bsrc + (size_t)(p + 1)*16384 + w*2048 + lane*16;
      char* l = ((char*)bstage[(p + 1) & 1]) + w*2048;
      GLL16(g, l); GLL16(g + 1024, l + 1024);
    }
    const u16* bb = bstage[p & 1];
    s8v bf[2][4];
    #pragma unroll
    for (int ks = 0; ks < 2; ++ks)
      #pragma unroll
      for (int nt = 0; nt < 4; ++nt)
        bf[ks][nt] = *(const s8v*)(bb + ks*4096 + ((wc*4 + nt)*64 + lane)*8);
    __builtin_amdgcn_s_setprio(1);
    #pragma unroll
    for (int mt = 0; mt < 4; ++mt){
      int yv = wr*4 + mt + dy - 1;
      if (yv >= 0 && yv <= 15){
        int px = yv*18 + l15 + dx;       // halo cols give zeros at x = -1/16
        #pragma unroll
        for (int ks = 0; ks < 2; ++ks){
          int su = (ks*4 + q) ^ (px & 7);
          s8v av = *(const s8v*)(img + px*64 + su*8);
          #pragma unroll
          for (int nt = 0; nt < 4; ++nt)
            acc[mt][nt] = __builtin_amdgcn_mfma_f32_16x16x32_bf16(av, bf[ks][nt], acc[mt][nt], 0, 0, 0);
        }
      }
    }
    __builtin_amdgcn_s_setprio(0);
    if (p < 8) asm volatile("s_waitcnt vmcnt(0)" ::: "memory");   // after full MFMA cover
    __builtin_amdgcn_s_barrier();   // raw: one barrier per tap
    asm volatile("" ::: "memory");
  }
  float s1v[4], s2v[4];
  #pragma unroll
  for (int nt = 0; nt < 4; ++nt){ s1v[nt] = 0.f; s2v[nt] = 0.f; }
  #pragma unroll
  for (int mp = 0; mp < 2; ++mp){
    #pragma unroll
    for (int rp = 0; rp < 2; ++rp){
      u16x4 pk;
      #pragma unroll
      for (int nt = 0; nt < 4; ++nt){
        float v0 = acc[2*mp][nt][2*rp];
        float v1 = acc[2*mp][nt][2*rp+1];
        float v2 = acc[2*mp+1][nt][2*rp];
        float v3 = acc[2*mp+1][nt][2*rp+1];
        s1v[nt] += v0 + v1 + v2 + v3;
        s2v[nt] += v0*v0 + v1*v1 + v2*v2 + v3*v3;
        pk[nt] = f2bf(fmaxf(fmaxf(v0, v1), fmaxf(v2, v3)));   // raw (BN2 absorbs alpha)
      }
      int opx = (wr*2 + mp)*8 + (q*2 + rp);  // pooled 8x8 index
      *(u16x4*)(p2raw + ((size_t)n*64 + opx)*128 + l15*8 + wc*4) = pk;
    }
  }
  #pragma unroll
  for (int nt = 0; nt < 4; ++nt){
    s1v[nt] += __shfl_xor(s1v[nt], 16); s1v[nt] += __shfl_xor(s1v[nt], 32);
    s2v[nt] += __shfl_xor(s2v[nt], 16); s2v[nt] += __shfl_xor(s2v[nt], 32);
  }
  __syncthreads();                 // all waves done reading img -> reuse as stats LDS
  float* ls = (float*)img;         // ls[0..127]=sum, ls[128..255]=sumsq
  if (t < 256) ls[t] = 0.f;
  __syncthreads();
  if (q == 0){
    #pragma unroll
    for (int nt = 0; nt < 4; ++nt){
      atomicAdd(&ls[l15*8 + wc*4 + nt], s1v[nt]);
      atomicAdd(&ls[128 + l15*8 + wc*4 + nt], s2v[nt]);
    }
  }
  __syncthreads();
  if (t < 128){ atomicAdd(gs + t, ls[t]); atomicAdd(gq + t, ls[128 + t]); }
}

// ---------- fc1 via MFMA. BN2+ReLU fused into the A-load; kb=8; R25: kb-partials
// atomicAdd directly into L2-resident h3 (h3p buffer deleted -> -16MB HBM). ----------
__global__ __launch_bounds__(256) void k_fc1m(const u16* __restrict__ p2, const u16* __restrict__ qfc1b,
                                              const float* __restrict__ s2, const float* __restrict__ q2,
                                              const float* __restrict__ g2, const float* __restrict__ b2,
                                              float* __restrict__ h3){
  int t = threadIdx.x;
  int bm = blockIdx.x, bn = blockIdx.y, kb = blockIdx.z;
  int w = t >> 6, lane = t & 63, l15 = lane & 15, q = lane >> 4;
  int wr = w >> 1, wc = w & 1;
  int rowbase = bm*32 + wr*16;
  int ntb = bn*8 + wc*4;
  const s8v* bp = (const s8v*)qfc1b;
  f4v acc[4];
  #pragma unroll
  for (int b = 0; b < 4; ++b) acc[b] = (f4v)(0.0f);
  #pragma unroll
  for (int ks4 = 0; ks4 < 4; ++ks4){
    int c0 = ks4*32 + q*8;
    float scv[8], biv[8];
    #pragma unroll
    for (int j = 0; j < 8; ++j){
      float m = s2[c0+j] * (1.f/262144.f);
      float var = q2[c0+j] * (1.f/262144.f) - m*m;
      float sc = g2[c0+j] * rsqrtf(var + 1e-5f);
      scv[j] = sc; biv[j] = b2[c0+j] - m*sc;
    }
    #pragma unroll 2
    for (int u = 0; u < 8; ++u){
      int ks = ks4 + u*4;
      int kst = kb*32 + ks;
      s8v bf[4];
      #pragma unroll
      for (int nt = 0; nt < 4; ++nt) bf[nt] = bp[(kst*16 + ntb + nt)*64 + lane];
      u16x8 araw = *(const u16x8*)(p2 + (size_t)(rowbase + l15)*8192 + kst*32 + q*8);
      s8v av;
      #pragma unroll
      for (int j = 0; j < 8; ++j){
        float f = fmaxf(bf2f(araw[j]) * scv[j] + biv[j], 0.f);
        ((u16*)&av)[j] = f2bf(f);
      }
      #pragma unroll
      for (int nt = 0; nt < 4; ++nt)
        acc[nt] = __builtin_amdgcn_mfma_f32_16x16x32_bf16(av, bf[nt], acc[nt], 0, 0, 0);
    }
  }
  #pragma unroll
  for (int nt = 0; nt < 4; ++nt){
    int col = (ntb + nt)*16 + l15;
    #pragma unroll
    for (int r = 0; r < 4; ++r)
      atomicAdd(&h3[(size_t)(rowbase + q*4 + r)*256 + col], acc[nt][r]);
  }
}

// ---------- BN3 stats over h3 (1MB, stats-only; h3 already complete). grid (8,32). ----------
__global__ __launch_bounds__(256) void k_fin3f(const float* __restrict__ h3,
                                               float* __restrict__ s3, float* __restrict__ q3){
  int jb = blockIdx.x, ns = blockIdx.y, t = threadIdx.x;
  int jj = t & 31, nn = t >> 5;
  int j = jb*32 + jj;
  float s1 = 0.f, s2 = 0.f;
  #pragma unroll
  for (int i = 0; i < 4; ++i){
    int n = ns*32 + i*8 + nn;
    float v = h3[(size_t)n*256 + j];
    s1 += v; s2 += v*v;
  }
  __shared__ float l1[256], l2[256];
  l1[t] = s1; l2[t] = s2;
  __syncthreads();
  if (t < 32){
    float a = 0.f, b = 0.f;
    #pragma unroll
    for (int k = 0; k < 8; ++k){ a += l1[t+32*k]; b += l2[t+32*k]; }
    atomicAdd(s3 + jb*32 + t, a); atomicAdd(q3 + jb*32 + t, b);
  }
}

// ---------- fc2: relu(bn3(h3)) @ sign(wfc2)^T -> out[1024,10] fp32. ----------
__global__ __launch_bounds__(256) void k_fc2(const float* __restrict__ h3, const float* __restrict__ qwfc2,
                                             const float* __restrict__ absum,
                                             const float* __restrict__ s3, const float* __restrict__ q3,
                                             const float* __restrict__ g3, const float* __restrict__ b3,
                                             float* __restrict__ out){
  int t = threadIdx.x;
  int n = blockIdx.x*4 + (t >> 6), lane = t & 63;
  float a[4];
  #pragma unroll
  for (int i = 0; i < 4; ++i){
    int j = lane + 64*i;
    float m = s3[j] * (1.f/1024.f);
    float var = q3[j] * (1.f/1024.f) - m*m;
    float sc = g3[j] * rsqrtf(var + 1e-5f);
    float v = h3[(size_t)n*256 + j] * sc + (b3[j] - m*sc);
    a[i] = fmaxf(v, 0.f);
  }
  float alpha = absum[3] * (1.f/2560.f);
  #pragma unroll
  for (int k = 0; k < 10; ++k){
    float p = 0.f;
    #pragma unroll
    for (int i = 0; i < 4; ++i) p += a[i] * qwfc2[k*256 + lane + 64*i];
    #pragma unroll
    for (int off = 32; off > 0; off >>= 1) p += __shfl_down(p, off);
    if (lane == 0) out[n*10 + k] = p * alpha;
  }
}

extern "C" void kernel_launch(void* const* d_in, const int* in_sizes, int n_in,
                              void* d_out, int out_size, void* d_ws, size_t ws_size,
                              hipStream_t stream){
  (void)in_sizes; (void)n_in; (void)out_size; (void)ws_size;
  const float* x    = (const float*)d_in[0];
  const float* w1   = (const float*)d_in[1];
  const float* g1   = (const float*)d_in[2];
  const float* b1   = (const float*)d_in[3];
  const float* w2   = (const float*)d_in[4];
  const float* g2   = (const float*)d_in[5];
  const float* b2   = (const float*)d_in[6];
  const float* wfc1 = (const float*)d_in[7];
  const float* g3   = (const float*)d_in[8];
  const float* b3   = (const float*)d_in[9];
  const float* wfc2 = (const float*)d_in[10];
  float* out = (float*)d_out;

  float* wsf = (float*)d_ws;
  char*  wsb = (char*)d_ws;
  float* absum = wsf;                                // [4] (only slot 3 used)
  float* s1 = wsf + 16;   float* q1 = wsf + 80;
  float* s2 = wsf + 144;  float* q2 = wsf + 272;
  float* s3 = wsf + 1024; float* q3 = wsf + 1280;
  u16*   qw1b  = (u16*)(wsf + 4096);                 // 2048 u16 conv1 B-frags
  u16*   qw2b  = (u16*)(wsb + (64u << 10));          // 144 KB bf16 B-frags
  float* qwfc2 = (float*)(wsb + (256u << 10));       // 10 KB fp32
  float* h3    = (float*)(wsb + (1ull << 20));       // 1 MB fp32 [1024][256] (zeroed in k_gen, atomic-accumulated)
  u16*   qfc1b = (u16*)(wsb + (2ull << 20));         // 4 MB bf16 B-frags
  u16*   p1t   = (u16*)(wsb + (8ull << 20) + 4096);  // 32 MB bf16 [1024][256][64] (permuted channels)
  u16*   p2    = (u16*)(wsb + (112ull << 20));       // 16 MB bf16 [1024][64][128] pooled raw (BN2 fused into fc1m)

  hipMemsetAsync(wsf, 0, 2048 * sizeof(float), stream);
  k_gen<<<562, 256, 0, stream>>>(w1, w2, wfc2, wfc1, qw1b, qw2b, qwfc2, qfc1b, absum, h3);
  k_conv1m<<<1024, 256, 0, stream>>>(x, qw1b, p1t, s1, q1);
  k_conv2m<<<1024, 512, 0, stream>>>(p1t, qw2b, s1, q1, g1, b1, p2, s2, q2);
  k_fc1m<<<dim3(32, 2, 8), 256, 0, stream>>>(p2, qfc1b, s2, q2, g2, b2, h3);
  k_fin3f<<<dim3(8, 32), 256, 0, stream>>>(h3, s3, q3);
  k_fc2<<<256, 256, 0, stream>>>(h3, qwfc2, absum, s3, q3, g3, b3, out);
}